// Round 4
// baseline (273.127 us; speedup 1.0000x reference)
//
#include <hip/hip_runtime.h>
#include <hip/hip_cooperative_groups.h>
#include <math.h>

namespace cg = cooperative_groups;

// Problem constants (from reference setup)
constexpr int B  = 32;
constexpr int C  = 64;
constexpr int H  = 128;
constexpr int W  = 128;
constexpr int HW = H * W;            // 16384
constexpr int SB = 2 * C * HW;       // per-batch stride in floats
constexpr float EPS = 1e-5f;

constexpr int NTHR  = 256;
constexpr int NBLK  = 512;            // 2048 plane-pairs / 4 per block
constexpr int NIT   = HW / (NTHR * 4); // 16 float4-iterations per plane
constexpr int PAIRS = 4;

typedef float v4f __attribute__((ext_vector_type(4)));

struct Coefs { float mr, mi, a00, a01, a10, a11, b0, b1; };

// ---------------------------------------------------------------------------
// Per-channel whitening coefficients from the 32 per-batch partials.
// Reference math implemented LITERALLY (t = sqrt(tau + 2*delta); s added to
// all four q entries).
// ---------------------------------------------------------------------------
__device__ __forceinline__ Coefs channel_coefs(const float* __restrict__ part,
                                               const float* __restrict__ gamma,
                                               const float* __restrict__ beta,
                                               int c) {
    float sr = 0.f, si = 0.f, srr = 0.f, sii = 0.f, sri = 0.f;
    const float* p = part + (size_t)c * B * 5;
#pragma unroll
    for (int b = 0; b < B; ++b) {
        sr  += p[b * 5 + 0];
        si  += p[b * 5 + 1];
        srr += p[b * 5 + 2];
        sii += p[b * 5 + 3];
        sri += p[b * 5 + 4];
    }
    const float N    = (float)(B * HW);
    const float invN = 1.f / N;
    Coefs o;
    o.mr = sr * invN;
    o.mi = si * invN;
    const float d = N - 1.f;

    const float covRR = (srr - N * o.mr * o.mr) / d;
    const float covII = (sii - N * o.mi * o.mi) / d;
    const float covRI = (sri - N * o.mr * o.mi) / d;

    const float m00 = covRR + EPS;
    const float m01 = covRI;
    const float m10 = covRI;
    const float m11 = covII + EPS;

    const float tau   = m00 + m11;
    const float delta = m00 * m11 - m01 * m10;
    const float s     = sqrtf(delta);
    const float t     = sqrtf(tau + 2.f * delta);   // reference: delta, not s

    const float q00 = (m00 + s) / t;
    const float q01 = (m01 + s) / t;
    const float q10 = (m10 + s) / t;
    const float q11 = (m11 + s) / t;

    const float det    = q00 * q11 - q01 * q10;
    const float invdet = 1.f / det;
    const float v00 =  q11 * invdet;
    const float v01 = -q01 * invdet;
    const float v10 = -q10 * invdet;
    const float v11 =  q00 * invdet;

    const float g00 = gamma[c * 4 + 0];
    const float g01 = gamma[c * 4 + 1];
    const float g10 = gamma[c * 4 + 2];
    const float g11 = gamma[c * 4 + 3];

    o.a00 = g00 * v00 + g01 * v10;
    o.a01 = g00 * v01 + g01 * v11;
    o.a10 = g10 * v00 + g11 * v10;
    o.a11 = g10 * v01 + g11 * v11;
    o.b0  = beta[c * 2 + 0];
    o.b1  = beta[c * 2 + 1];
    return o;
}

__device__ __forceinline__ void accum(const v4f r, const v4f i,
                                      float& sr, float& si,
                                      float& srr, float& sii, float& sri) {
    sr  += r.x + r.y + r.z + r.w;
    si  += i.x + i.y + i.z + i.w;
    srr += r.x * r.x + r.y * r.y + r.z * r.z + r.w * r.w;
    sii += i.x * i.x + i.y * i.y + i.z * i.z + i.w * i.w;
    sri += r.x * i.x + r.y * i.y + r.z * i.z + r.w * i.w;
}

__device__ __forceinline__ void reduce_and_store(float sr, float si, float srr,
                                                 float sii, float sri,
                                                 float (*red)[5],
                                                 float* __restrict__ part,
                                                 int c, int b) {
#pragma unroll
    for (int off = 32; off > 0; off >>= 1) {
        sr  += __shfl_down(sr,  off);
        si  += __shfl_down(si,  off);
        srr += __shfl_down(srr, off);
        sii += __shfl_down(sii, off);
        sri += __shfl_down(sri, off);
    }
    const int tid  = threadIdx.x;
    const int wave = tid >> 6;
    if ((tid & 63) == 0) {
        red[wave][0] = sr;  red[wave][1] = si;  red[wave][2] = srr;
        red[wave][3] = sii; red[wave][4] = sri;
    }
    __syncthreads();
    if (tid == 0) {
        float* dst = part + ((size_t)c * B + b) * 5;
#pragma unroll
        for (int k = 0; k < 5; ++k)
            dst[k] = red[0][k] + red[1][k] + red[2][k] + red[3][k];
    }
    __syncthreads();
}

__device__ __forceinline__ v4f whiten4(const v4f r, const v4f i, const Coefs& k) {
    v4f y;
    y.x = k.a00 * (r.x - k.mr) + k.a01 * (i.x - k.mi) + k.b0;
    y.y = k.a00 * (r.y - k.mr) + k.a01 * (i.y - k.mi) + k.b0;
    y.z = k.a00 * (r.z - k.mr) + k.a01 * (i.z - k.mi) + k.b0;
    y.w = k.a00 * (r.w - k.mr) + k.a01 * (i.w - k.mi) + k.b0;
    return y;
}
__device__ __forceinline__ v4f whiten4i(const v4f r, const v4f i, const Coefs& k) {
    v4f y;
    y.x = k.a10 * (r.x - k.mr) + k.a11 * (i.x - k.mi) + k.b1;
    y.y = k.a10 * (r.y - k.mr) + k.a11 * (i.y - k.mi) + k.b1;
    y.z = k.a10 * (r.z - k.mr) + k.a11 * (i.z - k.mi) + k.b1;
    y.w = k.a10 * (r.w - k.mr) + k.a11 * (i.w - k.mi) + k.b1;
    return y;
}

// ---------------------------------------------------------------------------
// Fused cooperative kernel. 512 blocks x 256 threads, 4 plane-pairs/block.
// Retention: pair 0 its 0..7 in regs (64 VGPR); pairs 1,2 its 0..3 in LDS
// (64 KB). 25% of x never re-read; rest expected L3-resident at grid.sync.
// ---------------------------------------------------------------------------
__global__ __launch_bounds__(NTHR, 2) void k_fused(const float* __restrict__ x,
                                                   const float* __restrict__ gamma,
                                                   const float* __restrict__ beta,
                                                   float* __restrict__ part,
                                                   float* __restrict__ out) {
    __shared__ v4f ldsR[2][4 * NTHR];   // 32 KB (pairs 1,2 / its 0..3)
    __shared__ v4f ldsI[2][4 * NTHR];   // 32 KB
    __shared__ float red[PAIRS][4][5];

    const int tid   = threadIdx.x;
    const int bid   = blockIdx.x;
    const int pair0 = PAIRS * bid;
    const int b     = pair0 >> 6;       // PAIRS divides C, so b uniform
    const int cbase = pair0 & 63;

    const float* xr[PAIRS];
    const float* xi[PAIRS];
#pragma unroll
    for (int p = 0; p < PAIRS; ++p) {
        xr[p] = x + (size_t)b * SB + (size_t)(cbase + p) * HW;
        xi[p] = xr[p] + (size_t)C * HW;
    }

    // ---------------- pass 1 ----------------
    v4f rr[8], ri[8];
    {   // pair 0: retain its 0..7 in registers
        float sr = 0.f, si = 0.f, srr = 0.f, sii = 0.f, sri = 0.f;
#pragma unroll
        for (int it = 0; it < 8; ++it) {
            const int idx = (it * NTHR + tid) * 4;
            rr[it] = *reinterpret_cast<const v4f*>(xr[0] + idx);
            ri[it] = *reinterpret_cast<const v4f*>(xi[0] + idx);
            accum(rr[it], ri[it], sr, si, srr, sii, sri);
        }
#pragma unroll
        for (int it = 8; it < NIT; ++it) {
            const int idx = (it * NTHR + tid) * 4;
            const v4f r = *reinterpret_cast<const v4f*>(xr[0] + idx);
            const v4f i = *reinterpret_cast<const v4f*>(xi[0] + idx);
            accum(r, i, sr, si, srr, sii, sri);
        }
        reduce_and_store(sr, si, srr, sii, sri, red[0], part, cbase + 0, b);
    }

#pragma unroll
    for (int p = 1; p <= 2; ++p) {   // pairs 1,2: retain its 0..3 in LDS
        float sr = 0.f, si = 0.f, srr = 0.f, sii = 0.f, sri = 0.f;
#pragma unroll
        for (int it = 0; it < 4; ++it) {
            const int idx = (it * NTHR + tid) * 4;
            const v4f r = *reinterpret_cast<const v4f*>(xr[p] + idx);
            const v4f i = *reinterpret_cast<const v4f*>(xi[p] + idx);
            ldsR[p - 1][it * NTHR + tid] = r;
            ldsI[p - 1][it * NTHR + tid] = i;
            accum(r, i, sr, si, srr, sii, sri);
        }
#pragma unroll
        for (int it = 4; it < NIT; ++it) {
            const int idx = (it * NTHR + tid) * 4;
            const v4f r = *reinterpret_cast<const v4f*>(xr[p] + idx);
            const v4f i = *reinterpret_cast<const v4f*>(xi[p] + idx);
            accum(r, i, sr, si, srr, sii, sri);
        }
        reduce_and_store(sr, si, srr, sii, sri, red[p], part, cbase + p, b);
    }

    {   // pair 3: no retention
        float sr = 0.f, si = 0.f, srr = 0.f, sii = 0.f, sri = 0.f;
#pragma unroll
        for (int it = 0; it < NIT; ++it) {
            const int idx = (it * NTHR + tid) * 4;
            const v4f r = *reinterpret_cast<const v4f*>(xr[3] + idx);
            const v4f i = *reinterpret_cast<const v4f*>(xi[3] + idx);
            accum(r, i, sr, si, srr, sii, sri);
        }
        reduce_and_store(sr, si, srr, sii, sri, red[3], part, cbase + 3, b);
    }

    __threadfence();
    cg::this_grid().sync();

    // ---------------- coefficients (uniform per block) ----------------
    const Coefs k0 = channel_coefs(part, gamma, beta, cbase + 0);
    const Coefs k1 = channel_coefs(part, gamma, beta, cbase + 1);
    const Coefs k2 = channel_coefs(part, gamma, beta, cbase + 2);
    const Coefs k3 = channel_coefs(part, gamma, beta, cbase + 3);

    float* orp[PAIRS];
    float* oip[PAIRS];
#pragma unroll
    for (int p = 0; p < PAIRS; ++p) {
        orp[p] = out + (size_t)b * SB + (size_t)(cbase + p) * HW;
        oip[p] = orp[p] + (size_t)C * HW;
    }

    // ---------------- pass 2 ----------------
    // pair 0 (regs for its<8)
#pragma unroll
    for (int it = 0; it < NIT; ++it) {
        const int idx = (it * NTHR + tid) * 4;
        v4f r, i;
        if (it < 8) { r = rr[it]; i = ri[it]; }
        else {
            r = __builtin_nontemporal_load(reinterpret_cast<const v4f*>(xr[0] + idx));
            i = __builtin_nontemporal_load(reinterpret_cast<const v4f*>(xi[0] + idx));
        }
        __builtin_nontemporal_store(whiten4(r, i, k0),  reinterpret_cast<v4f*>(orp[0] + idx));
        __builtin_nontemporal_store(whiten4i(r, i, k0), reinterpret_cast<v4f*>(oip[0] + idx));
    }
    // pairs 1,2 (LDS for its<4)
#pragma unroll
    for (int p = 1; p <= 2; ++p) {
        const Coefs& kk = (p == 1) ? k1 : k2;
#pragma unroll
        for (int it = 0; it < NIT; ++it) {
            const int idx = (it * NTHR + tid) * 4;
            v4f r, i;
            if (it < 4) { r = ldsR[p - 1][it * NTHR + tid]; i = ldsI[p - 1][it * NTHR + tid]; }
            else {
                r = __builtin_nontemporal_load(reinterpret_cast<const v4f*>(xr[p] + idx));
                i = __builtin_nontemporal_load(reinterpret_cast<const v4f*>(xi[p] + idx));
            }
            __builtin_nontemporal_store(whiten4(r, i, kk),  reinterpret_cast<v4f*>(orp[p] + idx));
            __builtin_nontemporal_store(whiten4i(r, i, kk), reinterpret_cast<v4f*>(oip[p] + idx));
        }
    }
    // pair 3
#pragma unroll
    for (int it = 0; it < NIT; ++it) {
        const int idx = (it * NTHR + tid) * 4;
        const v4f r = __builtin_nontemporal_load(reinterpret_cast<const v4f*>(xr[3] + idx));
        const v4f i = __builtin_nontemporal_load(reinterpret_cast<const v4f*>(xi[3] + idx));
        __builtin_nontemporal_store(whiten4(r, i, k3),  reinterpret_cast<v4f*>(orp[3] + idx));
        __builtin_nontemporal_store(whiten4i(r, i, k3), reinterpret_cast<v4f*>(oip[3] + idx));
    }
}

// ---------------------------------------------------------------------------
// Fallback pipeline (proven R2 path): partial sums + normalize.
// ---------------------------------------------------------------------------
__global__ __launch_bounds__(256) void k_partial(const float* __restrict__ x,
                                                 float* __restrict__ part) {
    const int c = blockIdx.x;
    const int b = blockIdx.y;
    const float* __restrict__ pxr = x + (size_t)b * SB + (size_t)c * HW;
    const float* __restrict__ pxi = pxr + (size_t)C * HW;
    const int tid = threadIdx.x;

    float sr = 0.f, si = 0.f, srr = 0.f, sii = 0.f, sri = 0.f;
#pragma unroll
    for (int it = 0; it < NIT; ++it) {
        const int idx = (it * 256 + tid) * 4;
        const v4f r = *reinterpret_cast<const v4f*>(pxr + idx);
        const v4f i = *reinterpret_cast<const v4f*>(pxi + idx);
        accum(r, i, sr, si, srr, sii, sri);
    }
    __shared__ float red[4][5];
    reduce_and_store(sr, si, srr, sii, sri, red, part, c, b);
}

__global__ __launch_bounds__(256) void k_norm(const float* __restrict__ x,
                                              const float* __restrict__ part,
                                              const float* __restrict__ gamma,
                                              const float* __restrict__ beta,
                                              float* __restrict__ out) {
    const int bc = blockIdx.y;
    const int b  = bc / C;
    const int c  = bc % C;
    const Coefs k = channel_coefs(part, gamma, beta, c);

    const size_t baseR = (size_t)b * SB + (size_t)c * HW;
    const size_t baseI = baseR + (size_t)C * HW;
    const int idx = (blockIdx.x * 256 + threadIdx.x) * 4;

    const v4f r = __builtin_nontemporal_load(reinterpret_cast<const v4f*>(x + baseR + idx));
    const v4f i = __builtin_nontemporal_load(reinterpret_cast<const v4f*>(x + baseI + idx));
    __builtin_nontemporal_store(whiten4(r, i, k),  reinterpret_cast<v4f*>(out + baseR + idx));
    __builtin_nontemporal_store(whiten4i(r, i, k), reinterpret_cast<v4f*>(out + baseI + idx));
}

// ---------------------------------------------------------------------------
extern "C" void kernel_launch(void* const* d_in, const int* in_sizes, int n_in,
                              void* d_out, int out_size, void* d_ws, size_t ws_size,
                              hipStream_t stream) {
    const float* x     = (const float*)d_in[0];
    const float* gamma = (const float*)d_in[1];
    const float* beta  = (const float*)d_in[2];
    float* out  = (float*)d_out;
    float* part = (float*)d_ws;           // C*B*5 = 10240 floats

    void* args[] = {(void*)&x, (void*)&gamma, (void*)&beta,
                    (void*)&part, (void*)&out};
    hipError_t err = hipLaunchCooperativeKernel((const void*)k_fused,
                                                dim3(NBLK), dim3(NTHR),
                                                args, 0, stream);
    if (err != hipSuccess) {
        // Cooperative path unavailable: proven two-kernel pipeline.
        k_partial<<<dim3(C, B), 256, 0, stream>>>(x, part);
        k_norm<<<dim3(HW / 1024, B * C), 256, 0, stream>>>(x, part, gamma, beta, out);
    }
}